// Round 1
// baseline (161.598 us; speedup 1.0000x reference)
//
#include <hip/hip_runtime.h>

// Causal quadratic linear attention:
//   S[h,n,d] = (1/32) * sum_{t<=n} (q_n . k_t)^2 * v_t[d]
//   Z[h,n]   = (1/32) * sum_{t<=n} (q_n . k_t)^2
// out = [S flat (8*4096*64) | Z flat (8*4096)]  (fp32)

#define SEQN 4096
#define NHEAD 8
#define DKEY 16
#define DVAL 64
#define KSTR 32     // Kl row stride (bf16); cols 16..31 are zeros (K=32 zero-pad)
#define VSTR 72     // Vt row stride (bf16); 144B = 9*16B -> aligned b128 reads

typedef float f32x4 __attribute__((ext_vector_type(4)));
typedef __bf16 bf16x8 __attribute__((ext_vector_type(8)));
typedef __bf16 bf16x2 __attribute__((ext_vector_type(2)));

__global__ __launch_bounds__(128, 2)
void taylor_fused(const float* __restrict__ Qg, const float* __restrict__ Kg,
                  const float* __restrict__ Vg, float* __restrict__ Og)
{
    __shared__ __align__(16) __bf16 Kl[64 * KSTR];  // [key][dim(0..15) | zeros(16..31)]
    __shared__ __align__(16) __bf16 Vt[64 * VSTR];  // [d][perm(key)] transposed V tile

    const int tid  = threadIdx.x;
    const int wv   = tid >> 6;       // wave 0..1
    const int lane = tid & 63;
    const int r    = lane & 15;
    const int g    = lane >> 4;

    const int bid = blockIdx.x;
    const int h   = bid & 7;                         // head -> XCD (L2 locality)
    const int tt  = bid >> 3;                        // 0..63
    const int qt  = (tt & 1) ? (tt >> 1) : (63 - (tt >> 1));  // heavy/light interleave
    const int qb  = qt * 64 + wv * 32;               // wave's first query row

    const float* __restrict__ Qh = Qg + (size_t)h * SEQN * DKEY;
    const float* __restrict__ Kh = Kg + (size_t)h * SEQN * DKEY;
    const float* __restrict__ Vh = Vg + (size_t)h * SEQN * DVAL;

    // zero Kl pad columns once (never overwritten afterwards)
    for (int row = tid; row < 64; row += 128) {
        bf16x8 z = {};
        *(bf16x8*)&Kl[row * KSTR + 16] = z;
        *(bf16x8*)&Kl[row * KSTR + 24] = z;
    }

    // Q fragments (B operand of S' MFMA): lane holds Q[qb+16uq+r][8g..8g+7], g>=2 zero
    bf16x8 qfrag[2];
    #pragma unroll
    for (int uq = 0; uq < 2; ++uq) {
        bf16x8 f = {};
        if (g < 2) {
            const float* qp = Qh + (size_t)(qb + 16 * uq + r) * DKEY + 8 * g;
            const f32x4 a = *(const f32x4*)qp;
            const f32x4 b = *(const f32x4*)(qp + 4);
            #pragma unroll
            for (int j = 0; j < 4; ++j) { f[j] = (__bf16)a[j]; f[4 + j] = (__bf16)b[j]; }
        }
        qfrag[uq] = f;
    }

    f32x4 oacc[2][4] = {};           // [uq][dt]  O^T accumulators
    float zacc0 = 0.f, zacc1 = 0.f;  // Z partials (per-lane, per uq)

    const int nkt = qt + 1;
    for (int kt = 0; kt < nkt; ++kt) {
        const int k0 = kt * 64;

        // ---- stage K tile: 64 keys x 16 dims, fp32 -> bf16 ----
        {
            const int key  = tid >> 1;
            const int half = tid & 1;
            const float* kp = Kh + (size_t)(k0 + key) * DKEY + 8 * half;
            const f32x4 a = *(const f32x4*)kp;
            const f32x4 b = *(const f32x4*)(kp + 4);
            bf16x8 kb;
            #pragma unroll
            for (int j = 0; j < 4; ++j) { kb[j] = (__bf16)a[j]; kb[4 + j] = (__bf16)b[j]; }
            *(bf16x8*)&Kl[key * KSTR + 8 * half] = kb;
        }
        // ---- stage V tile transposed, columns permuted so PV A-frag is one b128 ----
        // col(key): within each 32-key group, key 4q4+lo (hi=0) -> q4*8+lo,
        //           key 16+4q4+lo (hi=1) -> q4*8+4+lo   (matches S' reg packing)
        {
            const int d   = tid & 63;
            const int kp2 = (tid >> 6) * 2;
            #pragma unroll
            for (int i = 0; i < 16; ++i) {
                const int kk  = i * 4 + kp2;                  // even local key
                const float a0 = Vh[(size_t)(k0 + kk) * DVAL + d];
                const float a1 = Vh[(size_t)(k0 + kk + 1) * DVAL + d];
                const int w32 = kk & 31;
                const int col = (kk & 32) + ((w32 >> 2) & 3) * 8 + ((w32 >> 4) << 2) + (kk & 3);
                bf16x2 p; p[0] = (__bf16)a0; p[1] = (__bf16)a1;
                *(bf16x2*)&Vt[d * VSTR + col] = p;
            }
        }
        __syncthreads();

        const bool diag = (kt + 1 == nkt);
        #pragma unroll
        for (int ks = 0; ks < 2; ++ks) {
            if (k0 + 32 * ks < qb + 32) {    // wave-uniform; no barrier inside
                // V^T fragments (A operand of PV): row d = 16dt+r, slots = 8 perm cols
                bf16x8 vfrag[4];
                #pragma unroll
                for (int dt = 0; dt < 4; ++dt)
                    vfrag[dt] = *(const bf16x8*)&Vt[(16 * dt + r) * VSTR + 32 * ks + 8 * g];
                // K fragments (A operand of S'): row key = 32ks+16uk+r, slots dims 8g.. (g>=2 zeros)
                bf16x8 kf[2];
                #pragma unroll
                for (int uk = 0; uk < 2; ++uk)
                    kf[uk] = *(const bf16x8*)&Kl[(32 * ks + 16 * uk + r) * KSTR + 8 * g];

                const f32x4 zero4 = {};
                f32x4 s[2][2];
                #pragma unroll
                for (int uq = 0; uq < 2; ++uq)
                    #pragma unroll
                    for (int uk = 0; uk < 2; ++uk)
                        s[uq][uk] = __builtin_amdgcn_mfma_f32_16x16x32_bf16(
                            kf[uk], qfrag[uq], zero4, 0, 0, 0);
                // S' layout: col(lane&15)=q, row(4g+reg)=key  [m89-verified]

                #pragma unroll
                for (int uq = 0; uq < 2; ++uq) {
                    bf16x8 pf;
                    float zs = 0.f;
                    #pragma unroll
                    for (int uk = 0; uk < 2; ++uk) {
                        const int kGb = k0 + 32 * ks + 16 * uk + 4 * g;
                        const int qG  = qb + 16 * uq + r;
                        #pragma unroll
                        for (int i = 0; i < 4; ++i) {
                            const float sv = s[uq][uk][i];
                            float p = 0.03125f * sv * sv;       // alpha * (q.k)^2
                            if (diag && (kGb + i > qG)) p = 0.f; // causal mask
                            zs += p;
                            pf[4 * uk + i] = (__bf16)p;          // B-frag slot 4uk+i
                        }
                    }
                    if (uq == 0) zacc0 += zs; else zacc1 += zs;
                    #pragma unroll
                    for (int dt = 0; dt < 4; ++dt)
                        oacc[uq][dt] = __builtin_amdgcn_mfma_f32_16x16x32_bf16(
                            vfrag[dt], pf, oacc[uq][dt], 0, 0, 0);
                    // O^T layout: col(lane&15)=q, row(4g+reg)=d-offset
                }
            }
        }
        __syncthreads();
    }

    // ---- store S term: lane writes f32x4 at [q][16dt+4g .. +3] ----
    #pragma unroll
    for (int uq = 0; uq < 2; ++uq) {
        const int q = qb + 16 * uq + r;
        #pragma unroll
        for (int dt = 0; dt < 4; ++dt) {
            float* op = Og + ((size_t)h * SEQN + q) * DVAL + 16 * dt + 4 * g;
            *(f32x4*)op = oacc[uq][dt];
        }
    }
    // ---- store Z term: reduce the 4 lane-groups (keys are partitioned over g) ----
    zacc0 += __shfl_xor(zacc0, 16); zacc0 += __shfl_xor(zacc0, 32);
    zacc1 += __shfl_xor(zacc1, 16); zacc1 += __shfl_xor(zacc1, 32);
    if (lane < 16) {
        float* zp = Og + (size_t)NHEAD * SEQN * DVAL + (size_t)h * SEQN + qb;
        zp[r]      = zacc0;
        zp[16 + r] = zacc1;
    }
}

extern "C" void kernel_launch(void* const* d_in, const int* in_sizes, int n_in,
                              void* d_out, int out_size, void* d_ws, size_t ws_size,
                              hipStream_t stream) {
    const float* Q = (const float*)d_in[0];
    const float* K = (const float*)d_in[1];
    const float* V = (const float*)d_in[2];
    float* O = (float*)d_out;
    taylor_fused<<<dim3(512), dim3(128), 0, stream>>>(Q, K, V, O);
}

// Round 2
// 39.062 us; speedup vs baseline: 4.1370x; 4.1370x over previous
//
#include <hip/hip_runtime.h>

// Causal quadratic linear attention, chunked-scan formulation.
//   (q.k)^2 = sum_{i,j} q_i q_j k_i k_j   (256 ordered-pair features)
//   S[h,n,d] = alpha * [ Psi(q_n) . H_{<chunk}[.,d]  +  intra-chunk causal part ]
//   Z[h,n]   = same with V' column of ones.
// Phases: P0 convert K/V->bf16 (V transposed+permuted); P1 per-chunk state
// G^T[e,f]; P2 exclusive prefix over chunks -> Hb; P3 state-apply + intra.

#define SEQN 4096
#define NHEAD 8
#define DKEY 16
#define DVAL 64
#define CHUNK 256
#define NCHUNK 16           // SEQN / CHUNK
#define ALPHA 0.03125f

typedef float f32x4 __attribute__((ext_vector_type(4)));
typedef __bf16 bf16x8 __attribute__((ext_vector_type(8)));
typedef __bf16 bf16x2 __attribute__((ext_vector_type(2)));

__device__ inline float bf2f(__bf16 x) {
    unsigned short u = __builtin_bit_cast(unsigned short, x);
    unsigned int v = ((unsigned int)u) << 16;
    return __builtin_bit_cast(float, v);
}

// ---------------- Phase 0: K -> bf16, V -> bf16 transposed+permuted ----------------
// Vtg[h][kt][d][col], col = perm(local key) matching the S'->PV fragment packing.
__global__ __launch_bounds__(128, 2)
void p0_convert(const float* __restrict__ Kg, const float* __restrict__ Vg,
                __bf16* __restrict__ Kbf, __bf16* __restrict__ Vtg)
{
    __shared__ __align__(16) __bf16 Vt[64 * 72];
    const int tid = threadIdx.x;
    const int bid = blockIdx.x;
    const int h = bid >> 6, kt = bid & 63;
    const int k0 = kt * 64;
    // K convert: key = tid>>1, half = tid&1 (coalesced 16B writes)
    {
        const int key = tid >> 1, half = tid & 1;
        const float* kp = Kg + ((size_t)h * SEQN + k0 + key) * DKEY + 8 * half;
        const f32x4 a = *(const f32x4*)kp;
        const f32x4 b = *(const f32x4*)(kp + 4);
        bf16x8 o;
        #pragma unroll
        for (int j = 0; j < 4; ++j) { o[j] = (__bf16)a[j]; o[4 + j] = (__bf16)b[j]; }
        *(bf16x8*)&Kbf[((size_t)h * SEQN + k0 + key) * DKEY + 8 * half] = o;
    }
    // V transpose + perm into LDS
    {
        const int d = tid & 63;
        const int kp2 = (tid >> 6) * 2;   // 0 or 2
        #pragma unroll
        for (int i = 0; i < 16; ++i) {
            const int kk = i * 4 + kp2;
            const float a0 = Vg[((size_t)h * SEQN + k0 + kk) * DVAL + d];
            const float a1 = Vg[((size_t)h * SEQN + k0 + kk + 1) * DVAL + d];
            const int w32 = kk & 31;
            const int col = (kk & 32) + ((w32 >> 2) & 3) * 8 + ((w32 >> 4) << 2) + (kk & 3);
            bf16x2 p; p[0] = (__bf16)a0; p[1] = (__bf16)a1;
            *(bf16x2*)&Vt[d * 72 + col] = p;
        }
    }
    __syncthreads();
    // coalesced row write-out
    {
        const int d = tid >> 1, half = tid & 1;
        __bf16* vo = Vtg + (size_t)((h * 64 + kt) * 64 + d) * 64 + 32 * half;
        #pragma unroll
        for (int m = 0; m < 4; ++m)
            *(bf16x8*)&vo[8 * m] = *(const bf16x8*)&Vt[d * 72 + 32 * half + 8 * m];
    }
}

// ---------------- Phase 1: per-chunk state G^T[e][f] ----------------
// G^T(80x256) = V'^T(80xC) x Phi(Cx256); e: 0..63 = V dims, 64 = ones (Z), 65..79 pad.
#define VT2S 264    // bf16 row stride (16B-aligned rows, conflict-free b128 reads)
#define KTFS 268    // f32 row stride
__global__ __launch_bounds__(256, 1)
void p1_chunkstate(const float* __restrict__ Kg, const float* __restrict__ Vg,
                   __bf16* __restrict__ G)
{
    __shared__ __align__(16) __bf16 Vt2[80 * VT2S];
    __shared__ __align__(16) float  Ktf[16 * KTFS];
    const int tid = threadIdx.x;
    const int w = tid >> 6;
    const int lane = tid & 63;
    const int r = lane & 15, g = lane >> 4;
    const int h = blockIdx.x >> 4, c = blockIdx.x & 15;
    const int k0 = c * CHUNK;
    const float* __restrict__ Kh = Kg + (size_t)h * SEQN * DKEY;
    const float* __restrict__ Vh = Vg + (size_t)h * SEQN * DVAL;

    // static rows 64..79 of Vt2: row 64 = ones (t<256), rest zero
    for (int idx = tid; idx < 16 * VT2S; idx += 256) {
        const int row = idx / VT2S, t = idx - row * VT2S;
        Vt2[(64 + row) * VT2S + t] = (__bf16)((row == 0 && t < 256) ? 1.0f : 0.0f);
    }
    // V rows 0..63: thread e = tid&63 packs bf16x8 along t (conflict-free 16B writes)
    {
        const int e = tid & 63;
        const int tb0 = 8 * (tid >> 6);
        #pragma unroll
        for (int i = 0; i < 8; ++i) {
            const int tb = tb0 + 32 * i;
            bf16x8 v;
            #pragma unroll
            for (int j = 0; j < 8; ++j)
                v[j] = (__bf16)Vh[(size_t)(k0 + tb + j) * DVAL + e];
            *(bf16x8*)&Vt2[e * VT2S + tb] = v;
        }
    }
    // K transposed (fp32): thread t = tid handles all 16 dims
    {
        const int t = tid;
        const float* kp = Kh + (size_t)(k0 + t) * DKEY;
        #pragma unroll
        for (int m = 0; m < 4; ++m) {
            const f32x4 v = *(const f32x4*)(kp + 4 * m);
            #pragma unroll
            for (int j = 0; j < 4; ++j)
                Ktf[(4 * m + j) * KTFS + t] = v[j];
        }
    }
    __syncthreads();

    f32x4 acc[4][5] = {};  // [ftl][et]
    #pragma unroll
    for (int ks = 0; ks < 8; ++ks) {
        const int t0 = 32 * ks + 8 * g;
        bf16x8 af[5];
        #pragma unroll
        for (int et = 0; et < 5; ++et)
            af[et] = *(const bf16x8*)&Vt2[(16 * et + r) * VT2S + t0];
        const f32x4 kra = *(const f32x4*)&Ktf[r * KTFS + t0];
        const f32x4 krb = *(const f32x4*)&Ktf[r * KTFS + t0 + 4];
        #pragma unroll
        for (int ftl = 0; ftl < 4; ++ftl) {
            const int ft = 4 * w + ftl;
            const f32x4 kfa = *(const f32x4*)&Ktf[ft * KTFS + t0];
            const f32x4 kfb = *(const f32x4*)&Ktf[ft * KTFS + t0 + 4];
            bf16x8 bfrag;
            #pragma unroll
            for (int j = 0; j < 4; ++j) {
                bfrag[j]     = (__bf16)(kfa[j] * kra[j]);
                bfrag[4 + j] = (__bf16)(kfb[j] * krb[j]);
            }
            #pragma unroll
            for (int et = 0; et < 5; ++et)
                acc[ftl][et] = __builtin_amdgcn_mfma_f32_16x16x32_bf16(
                    af[et], bfrag, acc[ftl][et], 0, 0, 0);
        }
    }
    // write G[h][c][e][f] bf16
    __bf16* Gc = G + (size_t)((h * NCHUNK + c) * 80) * 256;
    #pragma unroll
    for (int ftl = 0; ftl < 4; ++ftl) {
        const int f = 16 * (4 * w + ftl) + r;
        #pragma unroll
        for (int et = 0; et < 5; ++et) {
            #pragma unroll
            for (int i = 0; i < 4; ++i) {
                const int e = 16 * et + 4 * g + i;
                Gc[e * 256 + f] = (__bf16)acc[ftl][et][i];
            }
        }
    }
}

// ---------------- Phase 2: exclusive prefix over chunks ----------------
__global__ void p2_prefix(const __bf16* __restrict__ G, __bf16* __restrict__ Hb)
{
    const int fid = blockIdx.x * 256 + threadIdx.x;   // < 8*80*256 = 163840
    const int h = fid / 20480;
    const int rem = fid - h * 20480;
    const size_t base = (size_t)h * NCHUNK * 20480 + rem;
    float acc = 0.f;
    #pragma unroll
    for (int cc = 0; cc < NCHUNK; ++cc) {
        Hb[base + (size_t)cc * 20480] = (__bf16)acc;
        acc += bf2f(G[base + (size_t)cc * 20480]);
    }
}

// ---------------- Phase 3: state apply + intra-chunk causal (LDS/barrier-free) ----------------
__global__ __launch_bounds__(64, 2)
void p3_attend(const float* __restrict__ Qg, const __bf16* __restrict__ Kbf,
               const __bf16* __restrict__ Vtg, const __bf16* __restrict__ Hb,
               float* __restrict__ Og)
{
    const int lane = threadIdx.x;
    const int r = lane & 15, g = lane >> 4;
    const int bid = blockIdx.x;
    const int h = bid & 7;           // head -> fixed XCD (L2 locality)
    const int qs = bid >> 3;         // 0..127, 32-query sub-tile
    const int qb = qs * 32;
    const int c = qs >> 3;           // chunk index

    // load q rows (fp32, static-indexed)
    float qr[2][16];
    #pragma unroll
    for (int uq = 0; uq < 2; ++uq) {
        const float* qp = Qg + ((size_t)h * SEQN + qb + 16 * uq + r) * DKEY;
        #pragma unroll
        for (int m = 0; m < 4; ++m) {
            const f32x4 v = *(const f32x4*)(qp + 4 * m);
            qr[uq][4 * m + 0] = v[0]; qr[uq][4 * m + 1] = v[1];
            qr[uq][4 * m + 2] = v[2]; qr[uq][4 * m + 3] = v[3];
        }
    }
    // lane's 8-dim slice selected by g&1 (static register indexing only)
    float qsel[2][8];
    #pragma unroll
    for (int uq = 0; uq < 2; ++uq)
        #pragma unroll
        for (int j = 0; j < 8; ++j)
            qsel[uq][j] = (g & 1) ? qr[uq][8 + j] : qr[uq][j];
    // bf16 Q fragment for S' MFMA (K=32 zero-pad for g>=2)
    bf16x8 qfrag[2];
    #pragma unroll
    for (int uq = 0; uq < 2; ++uq) {
        bf16x8 f = {};
        if (g < 2) {
            #pragma unroll
            for (int j = 0; j < 8; ++j) f[j] = (__bf16)qsel[uq][j];
        }
        qfrag[uq] = f;
    }

    f32x4 oacc[2][4] = {};
    f32x4 zacc4[2] = {};
    float zin0 = 0.f, zin1 = 0.f;

    // ---- state apply: O += Psi(q) x H_{<c} (8 K-steps over 256 features) ----
    if (c > 0) {
        const __bf16* Hc = Hb + (size_t)((h * NCHUNK + c) * 80) * 256;
        #pragma unroll
        for (int ks = 0; ks < 8; ++ks) {
            bf16x8 af[5];
            #pragma unroll
            for (int dt = 0; dt < 4; ++dt)
                af[dt] = *(const bf16x8*)&Hc[(16 * dt + r) * 256 + 32 * ks + 8 * g];
            af[4] = *(const bf16x8*)&Hc[(64 + r) * 256 + 32 * ks + 8 * g];
            #pragma unroll
            for (int uq = 0; uq < 2; ++uq) {
                const float qi = ALPHA * ((g & 2) ? qr[uq][2 * ks + 1] : qr[uq][2 * ks]);
                bf16x8 pf;
                #pragma unroll
                for (int j = 0; j < 8; ++j) pf[j] = (__bf16)(qi * qsel[uq][j]);
                #pragma unroll
                for (int dt = 0; dt < 4; ++dt)
                    oacc[uq][dt] = __builtin_amdgcn_mfma_f32_16x16x32_bf16(
                        af[dt], pf, oacc[uq][dt], 0, 0, 0);
                zacc4[uq] = __builtin_amdgcn_mfma_f32_16x16x32_bf16(
                    af[4], pf, zacc4[uq], 0, 0, 0);
            }
        }
    }

    // ---- intra-chunk causal tiles ----
    const int ktmax = qs >> 1;
    for (int kt = 4 * c; kt <= ktmax; ++kt) {
        const int k0 = kt * 64;
        const bool diag = (kt == ktmax);
        const __bf16* Vb = Vtg + (size_t)((h * 64 + kt) * 64) * 64;
        #pragma unroll
        for (int ks = 0; ks < 2; ++ks) {
            if (k0 + 32 * ks < qb + 32) {
                bf16x8 kf[2];
                #pragma unroll
                for (int uk = 0; uk < 2; ++uk) {
                    bf16x8 f = {};
                    if (g < 2)
                        f = *(const bf16x8*)&Kbf[((size_t)h * SEQN + k0 + 32 * ks + 16 * uk + r) * DKEY + 8 * g];
                    kf[uk] = f;
                }
                bf16x8 vf[4];
                #pragma unroll
                for (int dt = 0; dt < 4; ++dt)
                    vf[dt] = *(const bf16x8*)&Vb[(size_t)(16 * dt + r) * 64 + 32 * ks + 8 * g];

                const f32x4 zero4 = {};
                f32x4 s[2][2];
                #pragma unroll
                for (int uq = 0; uq < 2; ++uq)
                    #pragma unroll
                    for (int uk = 0; uk < 2; ++uk)
                        s[uq][uk] = __builtin_amdgcn_mfma_f32_16x16x32_bf16(
                            kf[uk], qfrag[uq], zero4, 0, 0, 0);

                #pragma unroll
                for (int uq = 0; uq < 2; ++uq) {
                    bf16x8 pf;
                    float zs = 0.f;
                    const int qG = qb + 16 * uq + r;
                    #pragma unroll
                    for (int uk = 0; uk < 2; ++uk) {
                        const int kGb = k0 + 32 * ks + 16 * uk + 4 * g;
                        #pragma unroll
                        for (int i = 0; i < 4; ++i) {
                            const float sv = s[uq][uk][i];
                            float p = ALPHA * sv * sv;
                            if (diag && (kGb + i > qG)) p = 0.f;
                            zs += p;
                            pf[4 * uk + i] = (__bf16)p;
                        }
                    }
                    if (uq == 0) zin0 += zs; else zin1 += zs;
                    #pragma unroll
                    for (int dt = 0; dt < 4; ++dt)
                        oacc[uq][dt] = __builtin_amdgcn_mfma_f32_16x16x32_bf16(
                            vf[dt], pf, oacc[uq][dt], 0, 0, 0);
                }
            }
        }
    }

    // ---- stores ----
    #pragma unroll
    for (int uq = 0; uq < 2; ++uq) {
        const int q = qb + 16 * uq + r;
        #pragma unroll
        for (int dt = 0; dt < 4; ++dt) {
            float* op = Og + ((size_t)h * SEQN + q) * DVAL + 16 * dt + 4 * g;
            *(f32x4*)op = oacc[uq][dt];
        }
    }
    zin0 += __shfl_xor(zin0, 16); zin0 += __shfl_xor(zin0, 32);
    zin1 += __shfl_xor(zin1, 16); zin1 += __shfl_xor(zin1, 32);
    if (lane < 16) {   // g==0 lanes hold the e=64 (Z) MFMA row in reg 0
        float* zp = Og + (size_t)NHEAD * SEQN * DVAL + (size_t)h * SEQN + qb;
        zp[r]      = zin0 + zacc4[0][0];
        zp[16 + r] = zin1 + zacc4[1][0];
    }
}

// ---------------- Fallback (R1 kernel) if workspace too small ----------------
__global__ __launch_bounds__(128, 2)
void taylor_mono(const float* __restrict__ Qg, const float* __restrict__ Kg,
                 const float* __restrict__ Vg, float* __restrict__ Og)
{
    __shared__ __align__(16) __bf16 Kl[64 * 32];
    __shared__ __align__(16) __bf16 Vt[64 * 72];
    const int tid = threadIdx.x;
    const int wv = tid >> 6;
    const int lane = tid & 63;
    const int r = lane & 15, g = lane >> 4;
    const int bid = blockIdx.x;
    const int h = bid & 7;
    const int tt = bid >> 3;
    const int qt = (tt & 1) ? (tt >> 1) : (63 - (tt >> 1));
    const int qb = qt * 64 + wv * 32;
    const float* __restrict__ Qh = Qg + (size_t)h * SEQN * DKEY;
    const float* __restrict__ Kh = Kg + (size_t)h * SEQN * DKEY;
    const float* __restrict__ Vh = Vg + (size_t)h * SEQN * DVAL;
    for (int row = tid; row < 64; row += 128) {
        bf16x8 z = {};
        *(bf16x8*)&Kl[row * 32 + 16] = z;
        *(bf16x8*)&Kl[row * 32 + 24] = z;
    }
    bf16x8 qfrag[2];
    #pragma unroll
    for (int uq = 0; uq < 2; ++uq) {
        bf16x8 f = {};
        if (g < 2) {
            const float* qp = Qh + (size_t)(qb + 16 * uq + r) * DKEY + 8 * g;
            const f32x4 a = *(const f32x4*)qp;
            const f32x4 b = *(const f32x4*)(qp + 4);
            #pragma unroll
            for (int j = 0; j < 4; ++j) { f[j] = (__bf16)a[j]; f[4 + j] = (__bf16)b[j]; }
        }
        qfrag[uq] = f;
    }
    f32x4 oacc[2][4] = {};
    float zacc0 = 0.f, zacc1 = 0.f;
    const int nkt = qt + 1;
    for (int kt = 0; kt < nkt; ++kt) {
        const int k0 = kt * 64;
        {
            const int key = tid >> 1, half = tid & 1;
            const float* kp = Kh + (size_t)(k0 + key) * DKEY + 8 * half;
            const f32x4 a = *(const f32x4*)kp;
            const f32x4 b = *(const f32x4*)(kp + 4);
            bf16x8 kb;
            #pragma unroll
            for (int j = 0; j < 4; ++j) { kb[j] = (__bf16)a[j]; kb[4 + j] = (__bf16)b[j]; }
            *(bf16x8*)&Kl[key * 32 + 8 * half] = kb;
        }
        {
            const int d = tid & 63;
            const int kp2 = (tid >> 6) * 2;
            #pragma unroll
            for (int i = 0; i < 16; ++i) {
                const int kk = i * 4 + kp2;
                const float a0 = Vh[(size_t)(k0 + kk) * DVAL + d];
                const float a1 = Vh[(size_t)(k0 + kk + 1) * DVAL + d];
                const int w32 = kk & 31;
                const int col = (kk & 32) + ((w32 >> 2) & 3) * 8 + ((w32 >> 4) << 2) + (kk & 3);
                bf16x2 p; p[0] = (__bf16)a0; p[1] = (__bf16)a1;
                *(bf16x2*)&Vt[d * 72 + col] = p;
            }
        }
        __syncthreads();
        const bool diag = (kt + 1 == nkt);
        #pragma unroll
        for (int ks = 0; ks < 2; ++ks) {
            if (k0 + 32 * ks < qb + 32) {
                bf16x8 vfrag[4];
                #pragma unroll
                for (int dt = 0; dt < 4; ++dt)
                    vfrag[dt] = *(const bf16x8*)&Vt[(16 * dt + r) * 72 + 32 * ks + 8 * g];
                bf16x8 kf[2];
                #pragma unroll
                for (int uk = 0; uk < 2; ++uk)
                    kf[uk] = *(const bf16x8*)&Kl[(32 * ks + 16 * uk + r) * 32 + 8 * g];
                const f32x4 zero4 = {};
                f32x4 s[2][2];
                #pragma unroll
                for (int uq = 0; uq < 2; ++uq)
                    #pragma unroll
                    for (int uk = 0; uk < 2; ++uk)
                        s[uq][uk] = __builtin_amdgcn_mfma_f32_16x16x32_bf16(
                            kf[uk], qfrag[uq], zero4, 0, 0, 0);
                #pragma unroll
                for (int uq = 0; uq < 2; ++uq) {
                    bf16x8 pf;
                    float zs = 0.f;
                    #pragma unroll
                    for (int uk = 0; uk < 2; ++uk) {
                        const int kGb = k0 + 32 * ks + 16 * uk + 4 * g;
                        const int qG = qb + 16 * uq + r;
                        #pragma unroll
                        for (int i = 0; i < 4; ++i) {
                            const float sv = s[uq][uk][i];
                            float p = 0.03125f * sv * sv;
                            if (diag && (kGb + i > qG)) p = 0.f;
                            zs += p;
                            pf[4 * uk + i] = (__bf16)p;
                        }
                    }
                    if (uq == 0) zacc0 += zs; else zacc1 += zs;
                    #pragma unroll
                    for (int dt = 0; dt < 4; ++dt)
                        oacc[uq][dt] = __builtin_amdgcn_mfma_f32_16x16x32_bf16(
                            vfrag[dt], pf, oacc[uq][dt], 0, 0, 0);
                }
            }
        }
        __syncthreads();
    }
    #pragma unroll
    for (int uq = 0; uq < 2; ++uq) {
        const int q = qb + 16 * uq + r;
        #pragma unroll
        for (int dt = 0; dt < 4; ++dt) {
            float* op = Og + ((size_t)h * SEQN + q) * DVAL + 16 * dt + 4 * g;
            *(f32x4*)op = oacc[uq][dt];
        }
    }
    zacc0 += __shfl_xor(zacc0, 16); zacc0 += __shfl_xor(zacc0, 32);
    zacc1 += __shfl_xor(zacc1, 16); zacc1 += __shfl_xor(zacc1, 32);
    if (lane < 16) {
        float* zp = Og + (size_t)NHEAD * SEQN * DVAL + (size_t)h * SEQN + qb;
        zp[r] = zacc0;
        zp[16 + r] = zacc1;
    }
}

extern "C" void kernel_launch(void* const* d_in, const int* in_sizes, int n_in,
                              void* d_out, int out_size, void* d_ws, size_t ws_size,
                              hipStream_t stream) {
    const float* Q = (const float*)d_in[0];
    const float* K = (const float*)d_in[1];
    const float* V = (const float*)d_in[2];
    float* O = (float*)d_out;

    const size_t G_OFF   = 0;                      // 8*16*80*256 bf16 = 5,242,880 B
    const size_t HB_OFF  = 5242880;                // same size
    const size_t KBF_OFF = 10485760;               // 8*4096*16 bf16 = 1,048,576 B
    const size_t VTG_OFF = 11534336;               // 8*64*64*64 bf16 = 4,194,304 B
    const size_t NEED    = 15728640;

    if (ws_size >= NEED) {
        char* ws = (char*)d_ws;
        __bf16* G   = (__bf16*)(ws + G_OFF);
        __bf16* Hb  = (__bf16*)(ws + HB_OFF);
        __bf16* Kbf = (__bf16*)(ws + KBF_OFF);
        __bf16* Vtg = (__bf16*)(ws + VTG_OFF);
        p0_convert   <<<dim3(512),  dim3(128), 0, stream>>>(K, V, Kbf, Vtg);
        p1_chunkstate<<<dim3(128),  dim3(256), 0, stream>>>(K, V, G);
        p2_prefix    <<<dim3(640),  dim3(256), 0, stream>>>(G, Hb);
        p3_attend    <<<dim3(1024), dim3(64),  0, stream>>>(Q, Kbf, Vtg, Hb, O);
    } else {
        taylor_mono<<<dim3(512), dim3(128), 0, stream>>>(Q, K, V, O);
    }
}